// Round 1
// baseline (998.556 us; speedup 1.0000x reference)
//
#include <hip/hip_runtime.h>
#include <cstddef>

// Problem constants (fixed by the reference).
#define DIM   256    // embedding dim
#define KCODE 8192   // num embeddings
#define NTOK  16384  // 16*1024 tokens
#define BT    128    // tokens per block tile
#define BK    64     // codes per K tile
#define DC    32     // D chunk staged in LDS
#define KS    8      // K-split factor (grid parallelism): 1024 blocks = 4/CU
#define KT_PER_SPLIT ((KCODE / BK) / KS)  // 16 K-tiles per block

// ws layout (floats): [0,8192) wn ; [8192, +KS*NTOK) partial vals ; then partial idx (int)

__global__ __launch_bounds__(256) void wnorm_kernel(const float* __restrict__ w,
                                                    float* __restrict__ wn) {
  const int lane = threadIdx.x & 63;
  const int k = blockIdx.x * 4 + (threadIdx.x >> 6);
  const float4 v = reinterpret_cast<const float4*>(w + (size_t)k * DIM)[lane];
  float s = v.x * v.x + v.y * v.y + v.z * v.z + v.w * v.w;
#pragma unroll
  for (int off = 32; off > 0; off >>= 1) s += __shfl_xor(s, off);
  if (lane == 0) wn[k] = s;
}

__global__ __launch_bounds__(256) void vq_partial_kernel(
    const float* __restrict__ x, const float* __restrict__ w,
    const float* __restrict__ wn, float* __restrict__ pv, int* __restrict__ pi) {
  __shared__ float As[DC * BT];  // A transposed: [d][tok], 16 KB
  __shared__ float Bs[DC * BK];  // B transposed: [d][k],   8 KB

  const int tid = threadIdx.x;
  const int split = blockIdx.x & (KS - 1);   // consecutive blocks -> different XCDs -> each L2 holds one 2MB weight slice
  const int tb = (blockIdx.x >> 3) * BT;
  const int cg = tid & 15;   // code group: 4 codes
  const int tg = tid >> 4;   // token group: 8 tokens

  float best_v[8];
  int best_i[8];
#pragma unroll
  for (int i = 0; i < 8; ++i) { best_v[i] = -3.4e38f; best_i[i] = 0; }

  const int a_tok = tid >> 1;
  const int b_kl = tid >> 2;

  for (int kt = split * KT_PER_SPLIT; kt < (split + 1) * KT_PER_SPLIT; ++kt) {
    float acc[8][4];
#pragma unroll
    for (int i = 0; i < 8; ++i)
#pragma unroll
      for (int j = 0; j < 4; ++j) acc[i][j] = 0.0f;

    for (int dc = 0; dc < DIM / DC; ++dc) {
      __syncthreads();
      {  // stage A chunk (transpose x tile into [d][tok])
        const float4* src =
            reinterpret_cast<const float4*>(x + (size_t)(tb + a_tok) * DIM + dc * DC);
#pragma unroll
        for (int r = 0; r < 4; ++r) {
          const int dq = (tid & 1) + 2 * r;
          const float4 v = src[dq];
          As[(dq * 4 + 0) * BT + a_tok] = v.x;
          As[(dq * 4 + 1) * BT + a_tok] = v.y;
          As[(dq * 4 + 2) * BT + a_tok] = v.z;
          As[(dq * 4 + 3) * BT + a_tok] = v.w;
        }
      }
      {  // stage B chunk (transpose weight tile into [d][k])
        const float4* src =
            reinterpret_cast<const float4*>(w + (size_t)(kt * BK + b_kl) * DIM + dc * DC);
#pragma unroll
        for (int r = 0; r < 2; ++r) {
          const int dq = (tid & 3) + 4 * r;
          const float4 v = src[dq];
          Bs[(dq * 4 + 0) * BK + b_kl] = v.x;
          Bs[(dq * 4 + 1) * BK + b_kl] = v.y;
          Bs[(dq * 4 + 2) * BK + b_kl] = v.z;
          Bs[(dq * 4 + 3) * BK + b_kl] = v.w;
        }
      }
      __syncthreads();
#pragma unroll 8
      for (int d = 0; d < DC; ++d) {
        // 3x ds_read_b128, 32 FMAs. A reads broadcast across cg (free); B reads 2-way (free).
        const float4 a0 = *reinterpret_cast<const float4*>(As + d * BT + tg * 8);
        const float4 a1 = *reinterpret_cast<const float4*>(As + d * BT + tg * 8 + 4);
        const float4 b = *reinterpret_cast<const float4*>(Bs + d * BK + cg * 4);
        const float a[8] = {a0.x, a0.y, a0.z, a0.w, a1.x, a1.y, a1.z, a1.w};
        const float bb[4] = {b.x, b.y, b.z, b.w};
#pragma unroll
        for (int i = 0; i < 8; ++i)
#pragma unroll
          for (int j = 0; j < 4; ++j) acc[i][j] += a[i] * bb[j];
      }
    }

    // per-K-tile epilogue: dist = ||w||^2 - 2*dot ; running argmax, lowest-k ties
    const float4 wv = *reinterpret_cast<const float4*>(wn + kt * BK + cg * 4);
    const int kbase = kt * BK + cg * 4;
#pragma unroll
    for (int i = 0; i < 8; ++i) {
      const float d0 = wv.x - 2.0f * acc[i][0];
      const float d1 = wv.y - 2.0f * acc[i][1];
      const float d2 = wv.z - 2.0f * acc[i][2];
      const float d3 = wv.w - 2.0f * acc[i][3];
      float bv = d0;
      int bj = 0;
      if (d1 > bv) { bv = d1; bj = 1; }
      if (d2 > bv) { bv = d2; bj = 2; }
      if (d3 > bv) { bv = d3; bj = 3; }
      if (bv > best_v[i]) { best_v[i] = bv; best_i[i] = kbase + bj; }
    }
  }

  // cross-cg reduction through LDS (reuse As/Bs)
  __syncthreads();
  float* red_v = As;                       // [tok][16] = 8 KB
  int* red_i = reinterpret_cast<int*>(Bs); // [tok][16] = 8 KB
#pragma unroll
  for (int i = 0; i < 8; ++i) {
    const int tok = tg * 8 + i;
    red_v[tok * 16 + cg] = best_v[i];
    red_i[tok * 16 + cg] = best_i[i];
  }
  __syncthreads();
  if (tid < BT) {
    float bv = red_v[tid * 16];
    int bi = red_i[tid * 16];
#pragma unroll
    for (int c = 1; c < 16; ++c) {
      const float v = red_v[tid * 16 + c];
      const int id = red_i[tid * 16 + c];
      if (v > bv || (v == bv && id < bi)) { bv = v; bi = id; }
    }
    pv[split * NTOK + tb + tid] = bv;
    pi[split * NTOK + tb + tid] = bi;
  }
}

__global__ __launch_bounds__(256) void vq_gather_kernel(
    const float* __restrict__ w, const float* __restrict__ pv,
    const int* __restrict__ pi, float* __restrict__ out) {
  const int lane = threadIdx.x & 63;
  const int n = blockIdx.x * 4 + (threadIdx.x >> 6);
  // splits cover ascending k ranges; strict > keeps the lowest-k winner
  float bv = pv[n];
  int bi = pi[n];
#pragma unroll
  for (int s = 1; s < KS; ++s) {
    const float v = pv[s * NTOK + n];
    if (v > bv) { bv = v; bi = pi[s * NTOK + n]; }
  }
  const float4 o = reinterpret_cast<const float4*>(w + (size_t)bi * DIM)[lane];
  reinterpret_cast<float4*>(out + (size_t)n * DIM)[lane] = o;
}

extern "C" void kernel_launch(void* const* d_in, const int* in_sizes, int n_in,
                              void* d_out, int out_size, void* d_ws, size_t ws_size,
                              hipStream_t stream) {
  const float* x = (const float*)d_in[0];
  const float* w = (const float*)d_in[1];
  float* out = (float*)d_out;

  float* wn = (float*)d_ws;              // 8192 floats
  float* pv = wn + KCODE;                // KS*NTOK floats
  int* pi = (int*)(pv + KS * NTOK);      // KS*NTOK ints  (total ~1.1 MB of ws)

  wnorm_kernel<<<KCODE / 4, 256, 0, stream>>>(w, wn);
  vq_partial_kernel<<<(NTOK / BT) * KS, 256, 0, stream>>>(x, w, wn, pv, pi);
  vq_gather_kernel<<<NTOK / 4, 256, 0, stream>>>(w, pv, pi, out);
}

// Round 2
// 526.504 us; speedup vs baseline: 1.8966x; 1.8966x over previous
//
#include <hip/hip_runtime.h>
#include <cstddef>
#include <cstdint>

#define DIM   256
#define KCODE 8192
#define NTOK  16384
#define NCB   64          // code blocks (8192/128)
#define MARGIN 1.0f
#define SA_STRIDE 72      // padded LDS row stride in bf16 elems (64 data + 8 pad)

typedef __attribute__((ext_vector_type(8))) short short8;
typedef __attribute__((ext_vector_type(8))) unsigned short ushort8;
typedef __attribute__((ext_vector_type(4))) float floatx4;

// RNE float->bf16 (matches HW round-to-nearest-even; inputs finite)
__device__ __forceinline__ unsigned short f2bf(float f) {
  uint32_t u = __builtin_bit_cast(uint32_t, f);
  return (unsigned short)((u + 0x7fffu + ((u >> 16) & 1u)) >> 16);
}

// ---- kernel 1: convert x,w to bf16; zero uncertain counter ----
__global__ __launch_bounds__(256) void prep_kernel(const float* __restrict__ x,
    const float* __restrict__ w, unsigned short* __restrict__ x0,
    unsigned short* __restrict__ w0, int* __restrict__ ucount) {
  if (blockIdx.x == 0 && threadIdx.x == 0) *ucount = 0;
  const int NU_X = NTOK * DIM / 8;   // 524288
  const int NU_W = KCODE * DIM / 8;  // 262144
  const int stride = gridDim.x * blockDim.x;
  for (int u = blockIdx.x * blockDim.x + threadIdx.x; u < NU_X + NU_W; u += stride) {
    const float* src;
    unsigned short* dst;
    if (u < NU_X) { src = x + (size_t)u * 8; dst = x0 + (size_t)u * 8; }
    else { src = w + (size_t)(u - NU_X) * 8; dst = w0 + (size_t)(u - NU_X) * 8; }
    const float4 f0 = ((const float4*)src)[0];
    const float4 f1 = ((const float4*)src)[1];
    ushort8 o;
    o[0] = f2bf(f0.x); o[1] = f2bf(f0.y); o[2] = f2bf(f0.z); o[3] = f2bf(f0.w);
    o[4] = f2bf(f1.x); o[5] = f2bf(f1.y); o[6] = f2bf(f1.z); o[7] = f2bf(f1.w);
    *(ushort8*)dst = o;
  }
}

// ---- kernel 2: row norms of w (wn) and x (sumx), one wave per row ----
__global__ __launch_bounds__(256) void norms_kernel(const float* __restrict__ w,
    const float* __restrict__ x, float* __restrict__ wn, float* __restrict__ sumx) {
  const int lane = threadIdx.x & 63;
  const int row = blockIdx.x * 4 + (threadIdx.x >> 6);  // 0..24575
  const float* src = (row < KCODE) ? (w + (size_t)row * DIM)
                                   : (x + (size_t)(row - KCODE) * DIM);
  const float4 v = ((const float4*)src)[lane];
  float s = v.x * v.x + v.y * v.y + v.z * v.z + v.w * v.w;
#pragma unroll
  for (int off = 32; off > 0; off >>= 1) s += __shfl_xor(s, off);
  if (lane == 0) {
    if (row < KCODE) wn[row] = s; else sumx[row - KCODE] = s;
  }
}

// ---- kernel 3: bf16 MFMA GEMM 128x128 tile + per-token top-2 epilogue ----
__global__ __launch_bounds__(256) void phase1_kernel(
    const unsigned short* __restrict__ x0, const unsigned short* __restrict__ w0,
    const float* __restrict__ wnorm,
    float* __restrict__ pv1, int* __restrict__ pc1, float* __restrict__ pv2) {
  __shared__ char smem[49152];
  unsigned short* As = (unsigned short*)smem;            // [128][72] bf16
  unsigned short* Bs = (unsigned short*)(smem + 18432);  // [128][72] bf16
  float* rv1 = (float*)smem;                             // [128][32] (epilogue reuse)
  int*   rc1 = (int*)(smem + 16384);
  float* rv2 = (float*)(smem + 32768);

  const int tid = threadIdx.x;
  const int cb = blockIdx.x & (NCB - 1);   // same-cb blocks land on one XCD (b%8 fixed)
  const int tb = blockIdx.x >> 6;
  const int lane = tid & 63;
  const int wv = tid >> 6;
  const int wm = wv & 1;        // token half (0/1)
  const int wnn = wv >> 1;      // code half (0/1)
  const int l15 = lane & 15, quad = lane >> 4;

  floatx4 acc[4][4];
#pragma unroll
  for (int mt = 0; mt < 4; ++mt)
#pragma unroll
    for (int nt = 0; nt < 4; ++nt) acc[mt][nt] = (floatx4){0.f, 0.f, 0.f, 0.f};

  // staging assignment: thread -> (row r, half h): 32 elems = 4x16B
  const int r = tid >> 1, h = tid & 1;
  const unsigned short* xrow = x0 + (size_t)(tb * 128 + r) * DIM + h * 32;
  const unsigned short* wrow = w0 + (size_t)(cb * 128 + r) * DIM + h * 32;
  unsigned short* adst = As + r * SA_STRIDE + h * 32;
  unsigned short* bdst = Bs + r * SA_STRIDE + h * 32;

  for (int kc = 0; kc < 4; ++kc) {
    __syncthreads();
    ushort8 a[4], b[4];
#pragma unroll
    for (int i = 0; i < 4; ++i) a[i] = ((const ushort8*)(xrow + kc * 64))[i];
#pragma unroll
    for (int i = 0; i < 4; ++i) b[i] = ((const ushort8*)(wrow + kc * 64))[i];
#pragma unroll
    for (int i = 0; i < 4; ++i) ((ushort8*)adst)[i] = a[i];
#pragma unroll
    for (int i = 0; i < 4; ++i) ((ushort8*)bdst)[i] = b[i];
    __syncthreads();
#pragma unroll
    for (int ks = 0; ks < 2; ++ks) {
      short8 af[4], bf[4];
#pragma unroll
      for (int mt = 0; mt < 4; ++mt)
        af[mt] = *(const short8*)(As + (wm * 64 + mt * 16 + l15) * SA_STRIDE + ks * 32 + quad * 8);
#pragma unroll
      for (int nt = 0; nt < 4; ++nt)
        bf[nt] = *(const short8*)(Bs + (wnn * 64 + nt * 16 + l15) * SA_STRIDE + ks * 32 + quad * 8);
#pragma unroll
      for (int mt = 0; mt < 4; ++mt)
#pragma unroll
        for (int nt = 0; nt < 4; ++nt)
          acc[mt][nt] = __builtin_amdgcn_mfma_f32_16x16x32_bf16(af[mt], bf[nt], acc[mt][nt], 0, 0, 0);
    }
  }

  // ---- epilogue: approx dist = wn - 2*dot; exact top-2 within block ----
  __syncthreads();  // staging reads done; smem is reused below
  float wnv[4];
#pragma unroll
  for (int nt = 0; nt < 4; ++nt)
    wnv[nt] = wnorm[cb * 128 + wnn * 64 + nt * 16 + l15];

#pragma unroll
  for (int mt = 0; mt < 4; ++mt) {
#pragma unroll
    for (int reg = 0; reg < 4; ++reg) {
      float v[4];
#pragma unroll
      for (int nt = 0; nt < 4; ++nt) v[nt] = wnv[nt] - 2.0f * acc[mt][nt][reg];
      float bv1 = v[0], bv2 = -3.4e38f;
      int bnt = 0;
#pragma unroll
      for (int j = 1; j < 4; ++j) {
        if (v[j] > bv1) { bv2 = bv1; bv1 = v[j]; bnt = j; }
        else bv2 = fmaxf(bv2, v[j]);
      }
      const int tok = wm * 64 + mt * 16 + quad * 4 + reg;  // C/D: row=quad*4+reg [m89/m91]
      const int cg = wnn * 16 + l15;                       // C/D: col=lane&15
      rv1[tok * 32 + cg] = bv1;
      rc1[tok * 32 + cg] = cb * 128 + wnn * 64 + bnt * 16 + l15;
      rv2[tok * 32 + cg] = bv2;
    }
  }
  __syncthreads();
  if (tid < 128) {
    float V1 = rv1[tid * 32], V2 = rv2[tid * 32];
    int C1 = rc1[tid * 32];
#pragma unroll 4
    for (int j = 1; j < 32; ++j) {
      const float v1 = rv1[tid * 32 + j], v2 = rv2[tid * 32 + j];
      const int c1 = rc1[tid * 32 + j];
      if (v1 > V1) { V2 = fmaxf(V1, v2); V1 = v1; C1 = c1; }
      else V2 = fmaxf(V2, v1);   // tie (v1==V1) -> V2=V1 -> gap 0 -> uncertain
    }
    const size_t o = (size_t)cb * NTOK + tb * 128 + tid;
    pv1[o] = V1; pc1[o] = C1; pv2[o] = V2;
  }
}

// ---- kernel 4: merge 64 col-block partials; emit final idx + uncertain list ----
__global__ __launch_bounds__(256) void reduce_kernel(
    const float* __restrict__ pv1, const int* __restrict__ pc1,
    const float* __restrict__ pv2, int* __restrict__ final_idx,
    int* __restrict__ ucount, int* __restrict__ ulist) {
  const int n = blockIdx.x * 256 + threadIdx.x;
  float V1 = -3.4e38f, V2 = -3.4e38f;
  int C1 = 0;
  for (int cb = 0; cb < NCB; ++cb) {
    const size_t o = (size_t)cb * NTOK + n;
    const float v1 = pv1[o], v2 = pv2[o];
    const int c1 = pc1[o];
    if (v1 > V1) { V2 = fmaxf(V1, v2); V1 = v1; C1 = c1; }
    else V2 = fmaxf(V2, v1);
  }
  final_idx[n] = C1;
  if (V1 - V2 < MARGIN) {
    const int p = atomicAdd(ucount, 1);
    ulist[p] = n;
  }
}

// ---- kernel 5: exact fp32 rescore of all codes for uncertain tokens ----
// block = (group g of 32 list slots) x (code slice sl of 1024); grid 512*8
__global__ __launch_bounds__(256) void phase2_kernel(
    const float* __restrict__ x, const float* __restrict__ w,
    const float* __restrict__ wnorm, const float* __restrict__ sumx,
    const int* __restrict__ ucount, const int* __restrict__ ulist,
    float* __restrict__ p2v, int* __restrict__ p2c) {
  const int uc = *ucount;
  const int g = blockIdx.x >> 3, sl = blockIdx.x & 7;  // sl<->XCD under round-robin
  if (g * 32 >= uc) return;
  __shared__ float xs[32][DIM];   // 32 KB
  __shared__ float sxs[32];
  __shared__ float wred_v[4][32];
  __shared__ int wred_c[4][32];
  const int tid = threadIdx.x;
#pragma unroll
  for (int q = 0; q < 8; ++q) {
    const int idx = q * 256 + tid;          // 0..2047
    const int i = idx >> 6, dq = idx & 63;
    const int s = g * 32 + i;
    const int tok = (s < uc) ? ulist[s] : ulist[g * 32];  // dummy = first valid
    ((float4*)&xs[i][0])[dq] = ((const float4*)(x + (size_t)tok * DIM))[dq];
  }
  if (tid < 32) {
    const int s = g * 32 + tid;
    const int tok = (s < uc) ? ulist[s] : ulist[g * 32];
    sxs[tid] = sumx[tok];
  }
  __syncthreads();

  float best_v[32];
  int best_c[32];
#pragma unroll
  for (int i = 0; i < 32; ++i) { best_v[i] = -3.4e38f; best_c[i] = 0; }

  for (int it = 0; it < 4; ++it) {
    const int c = sl * 1024 + it * 256 + tid;   // ascending within thread
    const float4* wr = (const float4*)(w + (size_t)c * DIM);
    float accv[32];
#pragma unroll
    for (int i = 0; i < 32; ++i) accv[i] = 0.f;
    for (int dq = 0; dq < 64; ++dq) {
      const float4 wvv = wr[dq];
#pragma unroll
      for (int i = 0; i < 32; ++i) {
        const float4 xv = ((const float4*)&xs[i][0])[dq];  // wave-uniform -> broadcast
        float a = accv[i];
        a = fmaf(xv.x, wvv.x, a);
        a = fmaf(xv.y, wvv.y, a);
        a = fmaf(xv.z, wvv.z, a);
        a = fmaf(xv.w, wvv.w, a);
        accv[i] = a;
      }
    }
    const float wnc = wnorm[c];
#pragma unroll
    for (int i = 0; i < 32; ++i) {
      const float dist = (sxs[i] + wnc) - 2.0f * accv[i];  // mimic ref op order
      if (dist > best_v[i]) { best_v[i] = dist; best_c[i] = c; }
    }
  }
  // reduce across 64 lanes (different codes), lowest-code ties
  const int lane = tid & 63, wvi = tid >> 6;
#pragma unroll
  for (int i = 0; i < 32; ++i) {
#pragma unroll
    for (int off = 1; off < 64; off <<= 1) {
      const float ov = __shfl_xor(best_v[i], off);
      const int oc = __shfl_xor(best_c[i], off);
      if (ov > best_v[i] || (ov == best_v[i] && oc < best_c[i])) {
        best_v[i] = ov; best_c[i] = oc;
      }
    }
  }
  if (lane == 0) {
#pragma unroll
    for (int i = 0; i < 32; ++i) { wred_v[wvi][i] = best_v[i]; wred_c[wvi][i] = best_c[i]; }
  }
  __syncthreads();
  if (tid < 32) {
    float V = wred_v[0][tid];
    int C = wred_c[0][tid];
#pragma unroll
    for (int k = 1; k < 4; ++k) {
      const float v = wred_v[k][tid];
      const int c = wred_c[k][tid];
      if (v > V || (v == V && c < C)) { V = v; C = c; }
    }
    p2v[(size_t)sl * NTOK + g * 32 + tid] = V;
    p2c[(size_t)sl * NTOK + g * 32 + tid] = C;
  }
}

// ---- kernel 6: merge 8 slices per uncertain token ----
__global__ __launch_bounds__(256) void p2merge_kernel(const int* __restrict__ ucount,
    const int* __restrict__ ulist, const float* __restrict__ p2v,
    const int* __restrict__ p2c, int* __restrict__ final_idx) {
  const int s = blockIdx.x * 256 + threadIdx.x;
  if (s >= *ucount) return;
  float V = -3.4e38f;
  int C = 0;
#pragma unroll
  for (int sl = 0; sl < 8; ++sl) {
    const float v = p2v[(size_t)sl * NTOK + s];
    const int c = p2c[(size_t)sl * NTOK + s];
    if (v > V || (v == V && c < C)) { V = v; C = c; }
  }
  final_idx[ulist[s]] = C;
}

// ---- kernel 7: gather output rows ----
__global__ __launch_bounds__(256) void gather_kernel(const float* __restrict__ w,
    const int* __restrict__ final_idx, float* __restrict__ out) {
  const int lane = threadIdx.x & 63;
  const int n = blockIdx.x * 4 + (threadIdx.x >> 6);
  const int bi = final_idx[n];
  ((float4*)(out + (size_t)n * DIM))[lane] = ((const float4*)(w + (size_t)bi * DIM))[lane];
}

extern "C" void kernel_launch(void* const* d_in, const int* in_sizes, int n_in,
                              void* d_out, int out_size, void* d_ws, size_t ws_size,
                              hipStream_t stream) {
  const float* x = (const float*)d_in[0];
  const float* w = (const float*)d_in[1];
  float* out = (float*)d_out;

  char* ws = (char*)d_ws;   // ~26.4 MB used
  unsigned short* x0 = (unsigned short*)(ws);                 // 8388608 B
  unsigned short* w0 = (unsigned short*)(ws + 8388608);       // 4194304 B
  float* wn   = (float*)(ws + 12582912);                      // 32768 B
  float* sumx = (float*)(ws + 12615680);                      // 65536 B
  float* pv1  = (float*)(ws + 12681216);                      // 4194304 B
  int*   pc1  = (int*)  (ws + 16875520);                      // 4194304 B
  float* pv2  = (float*)(ws + 21069824);                      // 4194304 B
  int* final_idx = (int*)(ws + 25264128);                     // 65536 B
  int* ucount = (int*)(ws + 25329664);                        // 64 B
  int* ulist  = (int*)(ws + 25329728);                        // 65536 B
  float* p2v  = (float*)(ws + 25395264);                      // 524288 B
  int*   p2c  = (int*)  (ws + 25919552);                      // 524288 B

  prep_kernel<<<1024, 256, 0, stream>>>(x, w, x0, w0, ucount);
  norms_kernel<<<(KCODE + NTOK) / 4, 256, 0, stream>>>(w, x, wn, sumx);
  phase1_kernel<<<(NTOK / 128) * NCB, 256, 0, stream>>>(x0, w0, wn, pv1, pc1, pv2);
  reduce_kernel<<<NTOK / 256, 256, 0, stream>>>(pv1, pc1, pv2, final_idx, ucount, ulist);
  phase2_kernel<<<(NTOK / 32) * 8, 256, 0, stream>>>(x, w, wn, sumx, ucount, ulist, p2v, p2c);
  p2merge_kernel<<<NTOK / 256, 256, 0, stream>>>(ucount, ulist, p2v, p2c, final_idx);
  gather_kernel<<<NTOK / 4, 256, 0, stream>>>(w, final_idx, out);
}